// Round 18
// baseline (42.337 us; speedup 1.0000x reference)
//
#include <hip/hip_runtime.h>
#include <hip/hip_bf16.h>

// QLSTM fused intra-block producer-consumer (R16) + R17 consumer tuning:
//   - ring reads prefetched one quad ahead (ds_read latency hidden under
//     the ~2800-cyc 4-step chain of the previous quad; race-free since
//     slot j&7 is released only after quad j's STEPs consumed its regs)
//   - s_setprio(1) on the consumer wave (T5: role-split regime)
//
// 128 blocks x 256 threads (4 waves, 1 block/CU -> wave-per-SIMD).
//   wave 0  = consumer: recurrence chain for 4 batch elements.
//   waves 1-3 = producers: split-bf16 MFMA, one 16x16 tile per t-quad.
// Sync: LDS flags + progress counter, WORKGROUP scope only.

#define T_STEPS 128
#define BATCH 512
#define IDIM 512

typedef __attribute__((ext_vector_type(8))) short bf16x8;
typedef __attribute__((ext_vector_type(4))) float f32x4;

#define INV2PI 0.15915494309189535f
#define L2E    1.4426950408889634f

static __device__ __forceinline__ short bfbits(__hip_bfloat16 h) {
    union { __hip_bfloat16 b; short s; } c; c.b = h; return c.s;
}

// DPP: quad_perm xor1=0xB1 xor2=0x4E xor3=0x1B; row_ror:n = 0x120|n.
template<int CTRL>
static __device__ __forceinline__ float qperm(float v) {
    return __int_as_float(__builtin_amdgcn_update_dpp(
        0, __float_as_int(v), CTRL, 0xF, 0xF, true));
}

static __device__ __forceinline__ float frcp(float v) {
    return __builtin_amdgcn_rcpf(v);
}

__global__ __launch_bounds__(256, 1) void qlstm_fused(
    const float* __restrict__ x,
    const float* __restrict__ Wf, const float* __restrict__ Wi,
    const float* __restrict__ Wu, const float* __restrict__ Wo,
    const float* __restrict__ bf, const float* __restrict__ bi,
    const float* __restrict__ bu, const float* __restrict__ bo,
    const float* __restrict__ thf, const float* __restrict__ thi,
    const float* __restrict__ thu, const float* __restrict__ tho,
    const float* __restrict__ kv,
    float* __restrict__ out)
{
    __shared__ __align__(16) unsigned short whi[16 * 64 * 8];  // 16 KB
    __shared__ __align__(16) unsigned short wlo[16 * 64 * 8];  // 16 KB
    __shared__ __align__(16) float kvl[IDIM];                  // 2 KB
    __shared__ float sxs[8][16][17];                           // ring: sx tiles
    __shared__ float d2s[8][16];                               // ring: d2 rows
    __shared__ int   flags[32];                                // quad ready
    __shared__ int   done;                                     // quads consumed

    const int tid  = threadIdx.x;   // 0..255
    const int wave = tid >> 6;      // 0..3
    const int lane = tid & 63;
    const int blk  = blockIdx.x;

    // ---- stage W as bf16 hi/lo MFMA B-fragments (1024 entries, 4/thread) ----
#pragma unroll
    for (int kk = 0; kk < 4; ++kk) {
        const int idx = tid + kk * 256;    // 0..1023 = (ks, lane)
        const int ks = idx >> 6;
        const int l  = idx & 63;
        const int c  = l & 15;
        const int bq = l >> 4;
        const int g  = c >> 2, q = c & 3;
        const float* Wsel = (g == 0) ? Wf : (g == 1) ? Wi : (g == 2) ? Wu : Wo;
        const float* src = Wsel + (size_t)q * 516 + ks * 32 + bq * 8;
        float4 w0 = *(const float4*)src;
        float4 w1 = *(const float4*)(src + 4);
        float wf8[8] = {w0.x, w0.y, w0.z, w0.w, w1.x, w1.y, w1.z, w1.w};
        unsigned short h8[8], l8[8];
#pragma unroll
        for (int j = 0; j < 8; ++j) {
            __hip_bfloat16 h = __float2bfloat16(wf8[j]);
            h8[j] = (unsigned short)bfbits(h);
            float r = wf8[j] - __bfloat162float(h);
            l8[j] = (unsigned short)bfbits(__float2bfloat16(r));
        }
        *(uint4*)&whi[idx * 8] = *(const uint4*)h8;
        *(uint4*)&wlo[idx * 8] = *(const uint4*)l8;
    }
    if (tid < 128)
        *(float4*)&kvl[tid * 4] = *(const float4*)(kv + tid * 4);
    if (tid < 32) flags[tid] = 0;
    if (tid == 32) done = 0;
    __syncthreads();   // ONLY barrier; roles diverge after this

    if (wave != 0) {
        // ================= producers (waves 1..3) =================
        const int row16 = lane & 15;        // tile row: tt*4+bb
        const int kb    = lane >> 4;        // k-chunk
        const int crow  = (lane >> 4) * 4;  // C-frag rows
        const int ccol  = lane & 15;        // C-frag col

        for (int j = wave - 1; j < 32; j += 3) {
            // ring space: slot j&7 free once consumer passed quad j-8
            while (__hip_atomic_load(&done, __ATOMIC_ACQUIRE,
                                     __HIP_MEMORY_SCOPE_WORKGROUP) < j - 7)
                __builtin_amdgcn_s_sleep(2);

            const float* px = x
                + ((size_t)(4 * j + (row16 >> 2)) * BATCH + blk * 4 + (row16 & 3)) * IDIM
                + kb * 8;

            float4 pA[4], pB[4];
#pragma unroll
            for (int i = 0; i < 4; ++i) {
                pA[i] = *(const float4*)(px + i * 32);
                pB[i] = *(const float4*)(px + i * 32 + 4);
            }
            f32x4 acc = {0.f, 0.f, 0.f, 0.f};
            float d2 = 0.f;

#pragma unroll
            for (int ks = 0; ks < 16; ++ks) {
                const int sl = ks & 3;
                float xf[8] = {pA[sl].x, pA[sl].y, pA[sl].z, pA[sl].w,
                               pB[sl].x, pB[sl].y, pB[sl].z, pB[sl].w};
                if (ks + 4 < 16) {   // 4-deep prefetch
                    pA[sl] = *(const float4*)(px + (ks + 4) * 32);
                    pB[sl] = *(const float4*)(px + (ks + 4) * 32 + 4);
                }
                const float* kvp = &kvl[ks * 32 + kb * 8];
                float4 kva = *(const float4*)kvp;
                float4 kvb = *(const float4*)(kvp + 4);
                float kvv[8] = {kva.x, kva.y, kva.z, kva.w,
                                kvb.x, kvb.y, kvb.z, kvb.w};
#pragma unroll
                for (int e = 0; e < 8; ++e) {
                    float dx = xf[e] - kvv[e];
                    d2 = fmaf(dx, dx, d2);
                }
                bf16x8 ah, al;
#pragma unroll
                for (int e = 0; e < 8; ++e) {
                    __hip_bfloat16 h = __float2bfloat16(xf[e]);
                    ah[e] = bfbits(h);
                    float r = xf[e] - __bfloat162float(h);
                    al[e] = bfbits(__float2bfloat16(r));
                }
                bf16x8 wh = *(const bf16x8*)&whi[(ks * 64 + lane) * 8];
                bf16x8 wl = *(const bf16x8*)&wlo[(ks * 64 + lane) * 8];
                acc = __builtin_amdgcn_mfma_f32_16x16x32_bf16(ah, wh, acc, 0, 0, 0);
                acc = __builtin_amdgcn_mfma_f32_16x16x32_bf16(al, wh, acc, 0, 0, 0);
                acc = __builtin_amdgcn_mfma_f32_16x16x32_bf16(ah, wl, acc, 0, 0, 0);
            }

            d2 += __shfl_xor(d2, 16);
            d2 += __shfl_xor(d2, 32);

            const int slot = j & 7;
#pragma unroll
            for (int e = 0; e < 4; ++e)
                sxs[slot][crow + e][ccol] = acc[e];
            if (lane < 16) d2s[slot][lane] = d2;
            // release: drains the ds_writes above before flag becomes visible
            __hip_atomic_store(&flags[j], 1, __ATOMIC_RELEASE,
                               __HIP_MEMORY_SCOPE_WORKGROUP);
        }
    } else {
        // ================= consumer (wave 0) =================
        __builtin_amdgcn_s_setprio(1);      // T5: critical wave priority

        const int s   = lane & 15;
        const int g   = s >> 2;
        const int q   = s & 3;
        const int b_l = lane >> 4;
        const int b   = blk * 4 + b_l;

        const float* W   = (g == 0) ? Wf  : (g == 1) ? Wi  : (g == 2) ? Wu  : Wo;
        const float* bb_ = (g == 0) ? bf  : (g == 1) ? bi  : (g == 2) ? bu  : bo;
        const float* th  = (g == 0) ? thf : (g == 1) ? thi : (g == 2) ? thu : tho;

        const float wh0 = W[(size_t)q * 516 + 512 + (q ^ 0)];
        const float wh1 = W[(size_t)q * 516 + 512 + (q ^ 1)];
        const float wh2 = W[(size_t)q * 516 + 512 + (q ^ 2)];
        const float wh3 = W[(size_t)q * 516 + 512 + (q ^ 3)];
        const float bias  = bb_[q];
        const float threv = th[q] * INV2PI;
        const float kh0 = kv[512 + (q ^ 0)];
        const float kh1 = kv[512 + (q ^ 1)];
        const float kh2 = kv[512 + (q ^ 2)];
        const float kh3 = kv[512 + (q ^ 3)];

        const bool g0m = (g == 0), g2m = (g == 2);
        const bool q0m = (q == 0), q1m = (q == 1);
        const bool qodd = (q & 1);

        const float c0 = g2m ? 0.999892f  : 0.250001f;
        const float c1 = g2m ? -0.330836f : -0.020794f;
        const float c2 = g2m ? 0.119567f  : 0.001852f;
        const float c3 = g2m ? -0.027029f : 0.f;
        const float off = g2m ? 0.f : 0.5f;

        float h0 = 0.f, h1 = 0.f, h2 = 0.f, h3 = 0.f, cx = 0.f;

        #define STEP(SX, D2X, t) do {                                          \
            float sxb = (SX) + bias;                                           \
            float gx  = __builtin_amdgcn_exp2f((D2X) * (-0.001f * L2E)) * INV2PI; \
            float dh0 = h0 - kh0, dh1 = h1 - kh1, dh2 = h2 - kh2, dh3 = h3 - kh3; \
            float d2h = fmaf(dh0, dh0, dh1 * dh1) + fmaf(dh2, dh2, dh3 * dh3); \
            float uu = d2h * 1.0e-3f;                                          \
            float gh = fmaf(uu, fmaf(0.5f, uu, -1.f), 1.f);                    \
            float gater = gh * gx;                                             \
            float p01 = fmaf(wh1, h1, fmaf(wh0, h0, sxb));                     \
            float p23 = fmaf(wh3, h3, wh2 * h2);                               \
            float pre = p01 + p23;                                             \
            float rev = fmaf(pre, gater, threv);                               \
            float cang = __builtin_amdgcn_cosf(__builtin_amdgcn_fractf(rev));  \
            float s1 = qperm<0xB1>(cang);                                      \
            float s2 = qperm<0x4E>(cang);                                      \
            float s3 = qperm<0x1B>(cang);                                      \
            float m23 = s2 * s3;                                               \
            float A  = q0m ? s1 : cang;                                        \
            float T1 = qodd ? s1 : 1.f;                                        \
            float T2 = q1m ? 1.f : m23;                                        \
            float z = A * T1 * T2;                                             \
            float zr = z * z;                                                  \
            float P  = fmaf(zr, fmaf(zr, fmaf(zr, c3, c2), c1), c0);           \
            float val = fmaf(z, P, off);                                       \
            float r4  = qperm<0x124>(val);                                     \
            float r8  = qperm<0x128>(val);                                     \
            float r12 = qperm<0x12C>(val);                                     \
            float f_ = g0m ? val : (g == 1) ? r4  : g2m ? r8  : r12;           \
            float i_ = g0m ? r12 : (g == 1) ? val : g2m ? r4  : r8;            \
            float u_ = g0m ? r8  : (g == 1) ? r12 : g2m ? val : r4;            \
            float o_ = g0m ? r4  : (g == 1) ? r8  : g2m ? r12 : val;           \
            float cn = fmaf(f_, cx, i_ * u_);                                  \
            float cr = cn * cn;                                                \
            float num = cn * fmaf(cr, cr + 105.f, 945.f);                      \
            float den = fmaf(cr, fmaf(cr, 15.f, 420.f), 945.f);                \
            float thc = num * frcp(den);                                       \
            float hn = o_ * thc;                                               \
            cx = cn;                                                           \
            h0 = hn;                                                           \
            h1 = qperm<0xB1>(hn);                                              \
            h2 = qperm<0x4E>(hn);                                              \
            h3 = qperm<0x1B>(hn);                                              \
            if (g0m) out[(size_t)(t) * (BATCH * 4) + b * 4 + q] = hn;          \
        } while (0)

        #define WAITQ(j) do {                                                  \
            while (__hip_atomic_load(&flags[j], __ATOMIC_ACQUIRE,              \
                                     __HIP_MEMORY_SCOPE_WORKGROUP) == 0)       \
                __builtin_amdgcn_s_sleep(1);                                   \
        } while (0)

        // ring-read prefetch: quad j+1's reads issued before quad j's steps
        float cs0, cs1, cs2, cs3, cd0, cd1, cd2, cd3;
        WAITQ(0);
        {
            cs0 = sxs[0][b_l][s];      cd0 = d2s[0][b_l];
            cs1 = sxs[0][4 + b_l][s];  cd1 = d2s[0][4 + b_l];
            cs2 = sxs[0][8 + b_l][s];  cd2 = d2s[0][8 + b_l];
            cs3 = sxs[0][12 + b_l][s]; cd3 = d2s[0][12 + b_l];
        }
        for (int j = 0; j < 32; ++j) {
            float ns0 = 0.f, ns1 = 0.f, ns2 = 0.f, ns3 = 0.f;
            float nd0 = 0.f, nd1 = 0.f, nd2 = 0.f, nd3 = 0.f;
            if (j < 31) {
                WAITQ(j + 1);                    // producers run ~8 ahead
                const int sn = (j + 1) & 7;      // issue reads; consumed next iter
                ns0 = sxs[sn][b_l][s];      nd0 = d2s[sn][b_l];
                ns1 = sxs[sn][4 + b_l][s];  nd1 = d2s[sn][4 + b_l];
                ns2 = sxs[sn][8 + b_l][s];  nd2 = d2s[sn][8 + b_l];
                ns3 = sxs[sn][12 + b_l][s]; nd3 = d2s[sn][12 + b_l];
            }
            STEP(cs0, cd0, 4 * j + 0);
            STEP(cs1, cd1, 4 * j + 1);
            STEP(cs2, cd2, 4 * j + 2);
            STEP(cs3, cd3, 4 * j + 3);
            // quad j consumed -> slot j&7 reusable (by quad j+8)
            __hip_atomic_store(&done, j + 1, __ATOMIC_RELEASE,
                               __HIP_MEMORY_SCOPE_WORKGROUP);
            cs0 = ns0; cs1 = ns1; cs2 = ns2; cs3 = ns3;
            cd0 = nd0; cd1 = nd1; cd2 = nd2; cd3 = nd3;
        }
        #undef WAITQ
        #undef STEP

        if (g0m) {
            const size_t base = (size_t)T_STEPS * BATCH * 4;
            out[base + (size_t)b * 4 + q] = h0;
            out[base + BATCH * 4 + (size_t)b * 4 + q] = cx;
        }
    }
}

extern "C" void kernel_launch(void* const* d_in, const int* in_sizes, int n_in,
                              void* d_out, int out_size, void* d_ws, size_t ws_size,
                              hipStream_t stream) {
    const float* x   = (const float*)d_in[0];
    const float* Wf  = (const float*)d_in[1];
    const float* bf  = (const float*)d_in[2];
    const float* Wi  = (const float*)d_in[3];
    const float* bi  = (const float*)d_in[4];
    const float* Wu  = (const float*)d_in[5];
    const float* bu  = (const float*)d_in[6];
    const float* Wo  = (const float*)d_in[7];
    const float* bo  = (const float*)d_in[8];
    const float* thf = (const float*)d_in[9];
    const float* thi = (const float*)d_in[10];
    const float* thu = (const float*)d_in[11];
    const float* tho = (const float*)d_in[12];
    const float* kv  = (const float*)d_in[13];
    float* out = (float*)d_out;

    qlstm_fused<<<128, 256, 0, stream>>>(x, Wf, Wi, Wu, Wo, bf, bi, bu, bo,
                                         thf, thi, thu, tho, kv, out);
}

// Round 19
// 41.553 us; speedup vs baseline: 1.0189x; 1.0189x over previous
//
#include <hip/hip_runtime.h>
#include <hip/hip_bf16.h>

// QLSTM fused intra-block producer-consumer — FINAL (R16 structure, best: 41.6us).
// qlayer(x,th) with c_w = cos(x_w+th_w): out = [c1c2c3, c0c1, c0c1c2, c0c1c2c3]
//
// 128 blocks x 256 threads (4 waves, 1 block/CU -> wave-per-SIMD).
//   wave 0  = consumer: recurrence chain for 4 batch elements (16 lanes each),
//             all cross-lane via DPP (quad_perm + row_ror), poly activations.
//   waves 1-3 = producers: split-bf16 MFMA (x_hi·W_hi + x_lo·W_hi + x_hi·W_lo),
//             one 16x16 sx tile (= 4 t-steps x 4 batches) per t-quad + exact d2.
// Sync: LDS flags + progress counter, WORKGROUP scope only (no cross-block).
// Wall time = 128 x chain-latency (~700 cyc/step) + ~4us startup — the serial
// recurrence floor; R9/R10/R12/R15/R17 micro-trims on the chain all null.

#define T_STEPS 128
#define BATCH 512
#define IDIM 512

typedef __attribute__((ext_vector_type(8))) short bf16x8;
typedef __attribute__((ext_vector_type(4))) float f32x4;

#define INV2PI 0.15915494309189535f
#define L2E    1.4426950408889634f

static __device__ __forceinline__ short bfbits(__hip_bfloat16 h) {
    union { __hip_bfloat16 b; short s; } c; c.b = h; return c.s;
}

// DPP: quad_perm xor1=0xB1 xor2=0x4E xor3=0x1B; row_ror:n = 0x120|n.
template<int CTRL>
static __device__ __forceinline__ float qperm(float v) {
    return __int_as_float(__builtin_amdgcn_update_dpp(
        0, __float_as_int(v), CTRL, 0xF, 0xF, true));
}

static __device__ __forceinline__ float frcp(float v) {
    return __builtin_amdgcn_rcpf(v);
}

__global__ __launch_bounds__(256, 1) void qlstm_fused(
    const float* __restrict__ x,
    const float* __restrict__ Wf, const float* __restrict__ Wi,
    const float* __restrict__ Wu, const float* __restrict__ Wo,
    const float* __restrict__ bf, const float* __restrict__ bi,
    const float* __restrict__ bu, const float* __restrict__ bo,
    const float* __restrict__ thf, const float* __restrict__ thi,
    const float* __restrict__ thu, const float* __restrict__ tho,
    const float* __restrict__ kv,
    float* __restrict__ out)
{
    __shared__ __align__(16) unsigned short whi[16 * 64 * 8];  // 16 KB
    __shared__ __align__(16) unsigned short wlo[16 * 64 * 8];  // 16 KB
    __shared__ __align__(16) float kvl[IDIM];                  // 2 KB
    __shared__ float sxs[8][16][17];                           // ring: sx tiles
    __shared__ float d2s[8][16];                               // ring: d2 rows
    __shared__ int   flags[32];                                // quad ready
    __shared__ int   done;                                     // quads consumed

    const int tid  = threadIdx.x;   // 0..255
    const int wave = tid >> 6;      // 0..3
    const int lane = tid & 63;
    const int blk  = blockIdx.x;

    // ---- stage W as bf16 hi/lo MFMA B-fragments (1024 entries, 4/thread) ----
#pragma unroll
    for (int kk = 0; kk < 4; ++kk) {
        const int idx = tid + kk * 256;    // 0..1023 = (ks, lane)
        const int ks = idx >> 6;
        const int l  = idx & 63;
        const int c  = l & 15;
        const int bq = l >> 4;
        const int g  = c >> 2, q = c & 3;
        const float* Wsel = (g == 0) ? Wf : (g == 1) ? Wi : (g == 2) ? Wu : Wo;
        const float* src = Wsel + (size_t)q * 516 + ks * 32 + bq * 8;
        float4 w0 = *(const float4*)src;
        float4 w1 = *(const float4*)(src + 4);
        float wf8[8] = {w0.x, w0.y, w0.z, w0.w, w1.x, w1.y, w1.z, w1.w};
        unsigned short h8[8], l8[8];
#pragma unroll
        for (int j = 0; j < 8; ++j) {
            __hip_bfloat16 h = __float2bfloat16(wf8[j]);
            h8[j] = (unsigned short)bfbits(h);
            float r = wf8[j] - __bfloat162float(h);
            l8[j] = (unsigned short)bfbits(__float2bfloat16(r));
        }
        *(uint4*)&whi[idx * 8] = *(const uint4*)h8;
        *(uint4*)&wlo[idx * 8] = *(const uint4*)l8;
    }
    if (tid < 128)
        *(float4*)&kvl[tid * 4] = *(const float4*)(kv + tid * 4);
    if (tid < 32) flags[tid] = 0;
    if (tid == 32) done = 0;
    __syncthreads();   // ONLY barrier; roles diverge after this

    if (wave != 0) {
        // ================= producers (waves 1..3) =================
        const int row16 = lane & 15;        // tile row: tt*4+bb
        const int kb    = lane >> 4;        // k-chunk
        const int crow  = (lane >> 4) * 4;  // C-frag rows
        const int ccol  = lane & 15;        // C-frag col

        for (int j = wave - 1; j < 32; j += 3) {
            // ring space: slot j&7 free once consumer passed quad j-8
            while (__hip_atomic_load(&done, __ATOMIC_ACQUIRE,
                                     __HIP_MEMORY_SCOPE_WORKGROUP) < j - 7)
                __builtin_amdgcn_s_sleep(2);

            const float* px = x
                + ((size_t)(4 * j + (row16 >> 2)) * BATCH + blk * 4 + (row16 & 3)) * IDIM
                + kb * 8;

            float4 pA[4], pB[4];
#pragma unroll
            for (int i = 0; i < 4; ++i) {
                pA[i] = *(const float4*)(px + i * 32);
                pB[i] = *(const float4*)(px + i * 32 + 4);
            }
            f32x4 acc = {0.f, 0.f, 0.f, 0.f};
            float d2 = 0.f;

#pragma unroll
            for (int ks = 0; ks < 16; ++ks) {
                const int sl = ks & 3;
                float xf[8] = {pA[sl].x, pA[sl].y, pA[sl].z, pA[sl].w,
                               pB[sl].x, pB[sl].y, pB[sl].z, pB[sl].w};
                if (ks + 4 < 16) {   // 4-deep prefetch
                    pA[sl] = *(const float4*)(px + (ks + 4) * 32);
                    pB[sl] = *(const float4*)(px + (ks + 4) * 32 + 4);
                }
                const float* kvp = &kvl[ks * 32 + kb * 8];
                float4 kva = *(const float4*)kvp;
                float4 kvb = *(const float4*)(kvp + 4);
                float kvv[8] = {kva.x, kva.y, kva.z, kva.w,
                                kvb.x, kvb.y, kvb.z, kvb.w};
#pragma unroll
                for (int e = 0; e < 8; ++e) {
                    float dx = xf[e] - kvv[e];
                    d2 = fmaf(dx, dx, d2);
                }
                bf16x8 ah, al;
#pragma unroll
                for (int e = 0; e < 8; ++e) {
                    __hip_bfloat16 h = __float2bfloat16(xf[e]);
                    ah[e] = bfbits(h);
                    float r = xf[e] - __bfloat162float(h);
                    al[e] = bfbits(__float2bfloat16(r));
                }
                bf16x8 wh = *(const bf16x8*)&whi[(ks * 64 + lane) * 8];
                bf16x8 wl = *(const bf16x8*)&wlo[(ks * 64 + lane) * 8];
                acc = __builtin_amdgcn_mfma_f32_16x16x32_bf16(ah, wh, acc, 0, 0, 0);
                acc = __builtin_amdgcn_mfma_f32_16x16x32_bf16(al, wh, acc, 0, 0, 0);
                acc = __builtin_amdgcn_mfma_f32_16x16x32_bf16(ah, wl, acc, 0, 0, 0);
            }

            d2 += __shfl_xor(d2, 16);
            d2 += __shfl_xor(d2, 32);

            const int slot = j & 7;
#pragma unroll
            for (int e = 0; e < 4; ++e)
                sxs[slot][crow + e][ccol] = acc[e];
            if (lane < 16) d2s[slot][lane] = d2;
            // release: drains the ds_writes above before flag becomes visible
            __hip_atomic_store(&flags[j], 1, __ATOMIC_RELEASE,
                               __HIP_MEMORY_SCOPE_WORKGROUP);
        }
    } else {
        // ================= consumer (wave 0) =================
        const int s   = lane & 15;
        const int g   = s >> 2;
        const int q   = s & 3;
        const int b_l = lane >> 4;
        const int b   = blk * 4 + b_l;

        const float* W   = (g == 0) ? Wf  : (g == 1) ? Wi  : (g == 2) ? Wu  : Wo;
        const float* bb_ = (g == 0) ? bf  : (g == 1) ? bi  : (g == 2) ? bu  : bo;
        const float* th  = (g == 0) ? thf : (g == 1) ? thi : (g == 2) ? thu : tho;

        const float wh0 = W[(size_t)q * 516 + 512 + (q ^ 0)];
        const float wh1 = W[(size_t)q * 516 + 512 + (q ^ 1)];
        const float wh2 = W[(size_t)q * 516 + 512 + (q ^ 2)];
        const float wh3 = W[(size_t)q * 516 + 512 + (q ^ 3)];
        const float bias  = bb_[q];
        const float threv = th[q] * INV2PI;
        const float kh0 = kv[512 + (q ^ 0)];
        const float kh1 = kv[512 + (q ^ 1)];
        const float kh2 = kv[512 + (q ^ 2)];
        const float kh3 = kv[512 + (q ^ 3)];

        const bool g0m = (g == 0), g2m = (g == 2);
        const bool q0m = (q == 0), q1m = (q == 1);
        const bool qodd = (q & 1);

        const float c0 = g2m ? 0.999892f  : 0.250001f;
        const float c1 = g2m ? -0.330836f : -0.020794f;
        const float c2 = g2m ? 0.119567f  : 0.001852f;
        const float c3 = g2m ? -0.027029f : 0.f;
        const float off = g2m ? 0.f : 0.5f;

        float h0 = 0.f, h1 = 0.f, h2 = 0.f, h3 = 0.f, cx = 0.f;

        #define STEP(SX, D2X, t) do {                                          \
            float sxb = (SX) + bias;                                           \
            float gx  = __builtin_amdgcn_exp2f((D2X) * (-0.001f * L2E)) * INV2PI; \
            float dh0 = h0 - kh0, dh1 = h1 - kh1, dh2 = h2 - kh2, dh3 = h3 - kh3; \
            float d2h = fmaf(dh0, dh0, dh1 * dh1) + fmaf(dh2, dh2, dh3 * dh3); \
            float uu = d2h * 1.0e-3f;                                          \
            float gh = fmaf(uu, fmaf(0.5f, uu, -1.f), 1.f);                    \
            float gater = gh * gx;                                             \
            float p01 = fmaf(wh1, h1, fmaf(wh0, h0, sxb));                     \
            float p23 = fmaf(wh3, h3, wh2 * h2);                               \
            float pre = p01 + p23;                                             \
            float rev = fmaf(pre, gater, threv);                               \
            float cang = __builtin_amdgcn_cosf(__builtin_amdgcn_fractf(rev));  \
            float s1 = qperm<0xB1>(cang);                                      \
            float s2 = qperm<0x4E>(cang);                                      \
            float s3 = qperm<0x1B>(cang);                                      \
            float m23 = s2 * s3;                                               \
            float A  = q0m ? s1 : cang;                                        \
            float T1 = qodd ? s1 : 1.f;                                        \
            float T2 = q1m ? 1.f : m23;                                        \
            float z = A * T1 * T2;                                             \
            float zr = z * z;                                                  \
            float P  = fmaf(zr, fmaf(zr, fmaf(zr, c3, c2), c1), c0);           \
            float val = fmaf(z, P, off);                                       \
            float r4  = qperm<0x124>(val);                                     \
            float r8  = qperm<0x128>(val);                                     \
            float r12 = qperm<0x12C>(val);                                     \
            float f_ = g0m ? val : (g == 1) ? r4  : g2m ? r8  : r12;           \
            float i_ = g0m ? r12 : (g == 1) ? val : g2m ? r4  : r8;            \
            float u_ = g0m ? r8  : (g == 1) ? r12 : g2m ? val : r4;            \
            float o_ = g0m ? r4  : (g == 1) ? r8  : g2m ? r12 : val;           \
            float cn = fmaf(f_, cx, i_ * u_);                                  \
            float cr = cn * cn;                                                \
            float num = cn * fmaf(cr, cr + 105.f, 945.f);                      \
            float den = fmaf(cr, fmaf(cr, 15.f, 420.f), 945.f);                \
            float thc = num * frcp(den);                                       \
            float hn = o_ * thc;                                               \
            cx = cn;                                                           \
            h0 = hn;                                                           \
            h1 = qperm<0xB1>(hn);                                              \
            h2 = qperm<0x4E>(hn);                                              \
            h3 = qperm<0x1B>(hn);                                              \
            if (g0m) out[(size_t)(t) * (BATCH * 4) + b * 4 + q] = hn;          \
        } while (0)

        for (int j = 0; j < 32; ++j) {
            while (__hip_atomic_load(&flags[j], __ATOMIC_ACQUIRE,
                                     __HIP_MEMORY_SCOPE_WORKGROUP) == 0)
                __builtin_amdgcn_s_sleep(1);
            const int slot = j & 7;
            float sx0 = sxs[slot][b_l][s],      dd0 = d2s[slot][b_l];
            float sx1 = sxs[slot][4 + b_l][s],  dd1 = d2s[slot][4 + b_l];
            float sx2 = sxs[slot][8 + b_l][s],  dd2 = d2s[slot][8 + b_l];
            float sx3 = sxs[slot][12 + b_l][s], dd3 = d2s[slot][12 + b_l];
            STEP(sx0, dd0, 4 * j + 0);
            STEP(sx1, dd1, 4 * j + 1);
            STEP(sx2, dd2, 4 * j + 2);
            STEP(sx3, dd3, 4 * j + 3);
            __hip_atomic_store(&done, j + 1, __ATOMIC_RELEASE,
                               __HIP_MEMORY_SCOPE_WORKGROUP);
        }
        #undef STEP

        if (g0m) {
            const size_t base = (size_t)T_STEPS * BATCH * 4;
            out[base + (size_t)b * 4 + q] = h0;
            out[base + BATCH * 4 + (size_t)b * 4 + q] = cx;
        }
    }
}

extern "C" void kernel_launch(void* const* d_in, const int* in_sizes, int n_in,
                              void* d_out, int out_size, void* d_ws, size_t ws_size,
                              hipStream_t stream) {
    const float* x   = (const float*)d_in[0];
    const float* Wf  = (const float*)d_in[1];
    const float* bf  = (const float*)d_in[2];
    const float* Wi  = (const float*)d_in[3];
    const float* bi  = (const float*)d_in[4];
    const float* Wu  = (const float*)d_in[5];
    const float* bu  = (const float*)d_in[6];
    const float* Wo  = (const float*)d_in[7];
    const float* bo  = (const float*)d_in[8];
    const float* thf = (const float*)d_in[9];
    const float* thi = (const float*)d_in[10];
    const float* thu = (const float*)d_in[11];
    const float* tho = (const float*)d_in[12];
    const float* kv  = (const float*)d_in[13];
    float* out = (float*)d_out;

    qlstm_fused<<<128, 256, 0, stream>>>(x, Wf, Wi, Wu, Wo, bf, bi, bu, bo,
                                         thf, thi, thu, tho, kv, out);
}